// Round 10
// baseline (445.151 us; speedup 1.0000x reference)
//
#include <hip/hip_runtime.h>
#include <hip/hip_bf16.h>
#include <stdint.h>

#define NN 8192
#define DIN 512
#define DOUT 256
#define NSPLIT 8
#define STRIP (NN / NSPLIT) /* 1024 */
#define KVBLK 64
#define NSTEP (STRIP / KVBLK) /* 16 */
#define LOG2E 1.4426950408889634f

typedef short short8 __attribute__((ext_vector_type(8)));
typedef float floatx4 __attribute__((ext_vector_type(4)));

__device__ __forceinline__ unsigned short f2bf_rne(float x) {
  unsigned u = __float_as_uint(x);
  u += 0x7fffu + ((u >> 16) & 1u);
  return (unsigned short)(u >> 16);
}

// packed RNE f32->bf16 pair: low16 = bf16(lo), high16 = bf16(hi)
__device__ __forceinline__ unsigned cvt_pk_bf16(float lo, float hi) {
  unsigned r;
  asm("v_cvt_pk_bf16_f32 %0, %1, %2" : "=v"(r) : "v"(lo), "v"(hi));
  return r;
}

// -------- weight transpose+cvt: W fp32 [512][256] -> WT bf16 [256][512] --------
__global__ __launch_bounds__(256) void kt_transpose(const float* __restrict__ Wg,
                                                    unsigned short* __restrict__ WT) {
  __shared__ unsigned short sm[32][33];
  int tid = threadIdx.x;
  int bk = blockIdx.x >> 3;  // k tile
  int bn = blockIdx.x & 7;   // n tile
  int k0 = bk * 32, n0 = bn * 32;
  int r = tid >> 3, c4 = (tid & 7) * 4;
  const float* src = Wg + (size_t)(k0 + r) * DOUT + n0 + c4;
#pragma unroll
  for (int x = 0; x < 4; ++x) sm[r][c4 + x] = f2bf_rne(src[x]);
  __syncthreads();
  unsigned short* dst = WT + (size_t)(n0 + r) * DIN + k0 + c4;
#pragma unroll
  for (int x = 0; x < 4; ++x) dst[x] = sm[c4 + x][r];
}

// -------- X fp32 [8192][512] -> Xb bf16 (aliases slab 0; gemm1 consumes Xb
//          before attn overwrites the slabs) --------
__global__ __launch_bounds__(256) void kt_cvtx(const float* __restrict__ X,
                                               unsigned short* __restrict__ Xb) {
  int g = blockIdx.x * 256 + threadIdx.x;  // one 8-float group per thread
  const float4* p = (const float4*)(X + (size_t)g * 8);
  float4 a = p[0], b = p[1];
  union { unsigned u[4]; short8 s8; } r;
  r.u[0] = cvt_pk_bf16(a.x, a.y);
  r.u[1] = cvt_pk_bf16(a.z, a.w);
  r.u[2] = cvt_pk_bf16(b.x, b.y);
  r.u[3] = cvt_pk_bf16(b.z, b.w);
  *(short8*)(Xb + (size_t)g * 8) = r.s8;
}

// -- GEMM1 (R5-proven LDS-staged structure; R9's blocked WhTb output kept):
//    WhTb[j>>5][d][j&31] so attn's staging reads are contiguous 16-KB blocks
//    (writer scatter profile unchanged: 4x32-B segments/instr either way). --
__global__ __launch_bounds__(256, 2) void kt_gemm1(const unsigned short* __restrict__ Xb,
                                                   const unsigned short* __restrict__ WT,
                                                   const float* __restrict__ Ab,
                                                   unsigned short* __restrict__ WhTb,
                                                   float* __restrict__ Wh1,
                                                   float* __restrict__ Wh2) {
  __shared__ __align__(16) unsigned short xs[64 * DIN];  // 64 KB
  int tid = threadIdx.x;
  int w = tid >> 6, lane = tid & 63;
  int col = lane & 15, q = lane >> 4;
  int ib = blockIdx.x & 127;  // i block (64 each)
  int db = blockIdx.x >> 7;   // d block (64 each)
  int i0 = ib * 64;

  // ---- stage X tile: thread owns row sr = tid>>2, chunks l = (tid&3) + 4n ----
  int sr = tid >> 2, sc = tid & 3, sxor = sr & 7;
  const unsigned short* gX = Xb + (size_t)(i0 + sr) * DIN + sc * 8;
  unsigned short* lX = xs + sr * DIN;
  short8 stg[8];
#pragma unroll
  for (int n = 0; n < 8; ++n) stg[n] = *(const short8*)(gX + n * 32);
#pragma unroll
  for (int n = 0; n < 8; ++n) {
    int l = sc + n * 4;
    *(short8*)(lX + ((l ^ sxor) * 8)) = stg[n];
  }
#pragma unroll
  for (int n = 8; n < 16; ++n) stg[n - 8] = *(const short8*)(gX + n * 32);
#pragma unroll
  for (int n = 8; n < 16; ++n) {
    int l = sc + n * 4;
    *(short8*)(lX + ((l ^ sxor) * 8)) = stg[n - 8];
  }

  // ---- prefetch all 16 A-frags (fly during the barrier drain) ----
  int drow = db * 64 + w * 16 + col;  // A row (d)
  const unsigned short* abase = WT + (size_t)drow * DIN + q * 8;
  short8 af[16];
#pragma unroll
  for (int s = 0; s < 16; ++s) af[s] = *(const short8*)(abase + s * 32);

  __syncthreads();

  floatx4 acc[4];
#pragma unroll
  for (int t = 0; t < 4; ++t) acc[t] = (floatx4)(0.0f);
  int cx = col & 7;  // reader XOR: (t*16+col)&7 == col&7
#pragma unroll
  for (int s = 0; s < 16; ++s) {
#pragma unroll
    for (int t = 0; t < 4; ++t) {
      short8 bf = *(const short8*)(xs + (t * 16 + col) * DIN + (((s * 4 + q) ^ cx) * 8));
      acc[t] = __builtin_amdgcn_mfma_f32_16x16x32_bf16(af[s], bf, acc[t], 0, 0, 0);
    }
  }

  // D: col=lane&15 -> i; row=q*4+r -> d  (layout verified vs anchor)
  int dq = db * 64 + w * 16 + q * 4;
  float a1v[4], a2v[4];
#pragma unroll
  for (int r = 0; r < 4; ++r) {
    a1v[r] = Ab[dq + r] * LOG2E;
    a2v[r] = Ab[DOUT + dq + r] * LOG2E;
  }
#pragma unroll
  for (int t = 0; t < 4; ++t) {
    floatx4 v = acc[t];
    int icol = i0 + t * 16 + col;  // attention j index
#pragma unroll
    for (int r = 0; r < 4; ++r)
      WhTb[((size_t)(icol >> 5) * DOUT + (dq + r)) * 32 + (icol & 31)] = f2bf_rne(v[r]);
    float p1 = v[0] * a1v[0] + v[1] * a1v[1] + v[2] * a1v[2] + v[3] * a1v[3];
    float p2 = v[0] * a2v[0] + v[1] * a2v[1] + v[2] * a2v[2] + v[3] * a2v[3];
    p1 += __shfl_xor(p1, 16);
    p1 += __shfl_xor(p1, 32);
    p2 += __shfl_xor(p2, 16);
    p2 += __shfl_xor(p2, 32);
    if (q == 0) {
      atomicAdd(&Wh1[icol], p1);
      atomicAdd(&Wh2[icol], p2);
    }
  }
}

// ---------------- fused masked-softmax attention (rank-1 scores) ----------------
// Max-free softmax is exact: |score*log2e| <= ~15, exp2 can't overflow; masked w=0.
// P weights rounded to bf16 (RNE) for MFMA; denominator sums the rounded weights.
// Wh1/Wh2 arrive pre-scaled by log2(e).
__device__ __forceinline__ short8 build_a(int4 pa, int4 pb, float wh1, floatx4 w2a,
                                          floatx4 w2b, float& lsum) {
  int av[8] = {pa.x, pa.y, pa.z, pa.w, pb.x, pb.y, pb.z, pb.w};
  float w2[8] = {w2a[0], w2a[1], w2a[2], w2a[3], w2b[0], w2b[1], w2b[2], w2b[3]};
  float wv[8];
#pragma unroll
  for (int e = 0; e < 8; ++e) {
    float sc = wh1 + w2[e];
    sc = fmaxf(sc, 0.2f * sc);  // LeakyReLU (commutes with the positive log2e scale)
    float ex = __builtin_amdgcn_exp2f(sc);
    wv[e] = (av[e] != 0) ? ex : 0.0f;
  }
  union { unsigned u[4]; short8 s8; } r;
#pragma unroll
  for (int p = 0; p < 4; ++p) {
    unsigned pk = cvt_pk_bf16(wv[2 * p], wv[2 * p + 1]);
    r.u[p] = pk;
    lsum += __uint_as_float(pk << 16) + __uint_as_float(pk & 0xffff0000u);
  }
  return r.s8;
}

// R10 attn: R8 structure with blocked-WhTb staging, COVERAGE FIXED vs R9.
// Per step the tile is 32 KB = 8 x short8/thread (R9 staged only 2 -> NaN).
// Block n (16 KB, [256 d][32 j]): linear e = tid*8 + m*2048 -> d = (tid>>2)+m*64,
// sub-chunk c = tid&3. 8 loads/thread/step (same count as R8) but each is
// wave-contiguous 1 KB (was 64 distinct 16-KB-strided lines per instr).
// LDS write: row d, logical chunk n*4+c, phys ^= (d&7) = ((tid>>2)&7) for all m.
// Reader (phys = logical ^ (col&7)), adj, build_a, epilogue: byte-identical R8.
__global__ __launch_bounds__(256, 2) void kt_attn(const int* __restrict__ adj,
                                                  const unsigned short* __restrict__ WhTb,
                                                  const float* __restrict__ Wh1,
                                                  const float* __restrict__ Wh2,
                                                  float* __restrict__ accs,
                                                  float* __restrict__ lgp) {
  __shared__ __align__(16) unsigned short tileB[2][DOUT * KVBLK];  // 2 x 32 KB
  __shared__ __align__(16) float wh2s[STRIP];                      // 4 KB
  int tid = threadIdx.x;
  int w = tid >> 6, lane = tid & 63;
  int col = lane & 15, q = lane >> 4;
  int s = blockIdx.x & (NSPLIT - 1);  // strip -> XCD: WhTb strip stays in that L2
  int ib = blockIdx.x >> 3;
  int i0 = ib * 128;
  int jb = s * STRIP;

  // Wh2 strip -> LDS once (256 threads x float4 = 1024 floats)
  ((float4*)wh2s)[tid] = ((const float4*)(Wh2 + jb))[tid];

  int r0 = i0 + w * 32 + col;  // this lane's first score row
  float wh1r0 = Wh1[r0];
  float wh1r1 = Wh1[r0 + 16];

  // blocked staging: strip = 32 j-blocks of 16 KB; step k consumes blocks
  // 2k, 2k+1. Thread covers (d = (tid>>2)+m*64, c = tid&3) per block, m=0..3.
  const unsigned short* gW = WhTb + (size_t)(s * 32) * 8192 + tid * 8;
  int scn = tid & 3, sx = (tid >> 2) & 7;
  unsigned short* lrow0 = &tileB[0][(tid >> 2) * KVBLK];
  int wo[2];  // phys chunk byte offsets for n=0,1 (logical n*4+c)
  wo[0] = ((scn ^ sx) * 8);
  wo[1] = (((4 + scn) ^ sx) * 8);

  // reader: row d = t*16+col (d&7 == col&7); logical chunk q / 4+q
  int ck = col & 7;
  int off0 = col * KVBLK + ((q ^ ck) * 8);        // half 0 (chunk q)
  int off1 = col * KVBLK + (((4 + q) ^ ck) * 8);  // half 1 (chunk 4+q)
  const unsigned short* tb0 = &tileB[0][0];

  const int* aptr0 = adj + ((size_t)r0 << 13) + jb + q * 8;
  const int* aptr1 = adj + ((size_t)(r0 + 16) << 13) + jb + q * 8;

  floatx4 acc0[16], acc1[16];
#pragma unroll
  for (int t = 0; t < 16; ++t) {
    acc0[t] = (floatx4)(0.0f);
    acc1[t] = (floatx4)(0.0f);
  }
  float lp0 = 0.f, lp1 = 0.f;

  // prologue prefetch: step-0 tile (blocks 0,1; 4 chunks each) + adj halves
  short8 st[8];
#pragma unroll
  for (int n = 0; n < 2; ++n)
#pragma unroll
    for (int m = 0; m < 4; ++m)
      st[n * 4 + m] = *(const short8*)(gW + n * 8192 + m * 2048);
  int4 aA0a = *(const int4*)aptr0;          // h0 row0
  int4 aA0b = *(const int4*)(aptr0 + 4);
  int4 aA1a = *(const int4*)aptr1;          // h0 row1
  int4 aA1b = *(const int4*)(aptr1 + 4);
  int4 aB0a = *(const int4*)(aptr0 + 32);   // h1 row0
  int4 aB0b = *(const int4*)(aptr0 + 36);
  int4 aB1a = *(const int4*)(aptr1 + 32);   // h1 row1
  int4 aB1b = *(const int4*)(aptr1 + 36);

#pragma unroll 1
  for (int k = 0; k < NSTEP; ++k) {
    int bsel = (k & 1) * (DOUT * KVBLK);
    unsigned short* lw = lrow0 + bsel;
#pragma unroll
    for (int n = 0; n < 2; ++n)
#pragma unroll
      for (int m = 0; m < 4; ++m)
        *(short8*)(lw + m * (64 * KVBLK) + wo[n]) = st[n * 4 + m];
    if (k + 1 < NSTEP) {  // issue next stage loads before the barrier wait
      const unsigned short* gs = gW + (size_t)(2 * (k + 1)) * 8192;
#pragma unroll
      for (int n = 0; n < 2; ++n)
#pragma unroll
        for (int m = 0; m < 4; ++m)
          st[n * 4 + m] = *(const short8*)(gs + n * 8192 + m * 2048);
    }
    // lgkm-only barrier (R3/R5-proven): ds_writes visible, prior ds_reads
    // retired; global prefetches keep flying across it. Also covers the
    // prologue wh2s ds_write on the first iteration.
    asm volatile("s_waitcnt lgkmcnt(0)\ns_barrier" ::: "memory");
    int jl = k * KVBLK;
    // ---------------- half 0 (j = jl .. jl+32) ----------------
    {
      floatx4 w2a = *(const floatx4*)&wh2s[jl + q * 8];
      floatx4 w2b = *(const floatx4*)&wh2s[jl + q * 8 + 4];
      short8 af0 = build_a(aA0a, aA0b, wh1r0, w2a, w2b, lp0);
      short8 af1 = build_a(aA1a, aA1b, wh1r1, w2a, w2b, lp1);
      if (k + 1 < NSTEP) {  // reload h0 adj for step k+1 (full step of flight)
        int jn = (k + 1) * KVBLK;
        aA0a = *(const int4*)(aptr0 + jn);
        aA0b = *(const int4*)(aptr0 + jn + 4);
        aA1a = *(const int4*)(aptr1 + jn);
        aA1b = *(const int4*)(aptr1 + jn + 4);
      }
      const unsigned short* br = tb0 + bsel + off0;
#pragma unroll
      for (int h = 0; h < 4; ++h) {
        short8 bf[4];
#pragma unroll
        for (int t = 0; t < 4; ++t) bf[t] = *(const short8*)(br + (h * 4 + t) * 1024);
#pragma unroll
        for (int t = 0; t < 4; ++t) {
          acc0[h * 4 + t] =
              __builtin_amdgcn_mfma_f32_16x16x32_bf16(af0, bf[t], acc0[h * 4 + t], 0, 0, 0);
          acc1[h * 4 + t] =
              __builtin_amdgcn_mfma_f32_16x16x32_bf16(af1, bf[t], acc1[h * 4 + t], 0, 0, 0);
        }
      }
    }
    // ---------------- half 1 (j = jl+32 .. jl+64) ----------------
    {
      floatx4 w2a = *(const floatx4*)&wh2s[jl + 32 + q * 8];
      floatx4 w2b = *(const floatx4*)&wh2s[jl + 32 + q * 8 + 4];
      short8 ag0 = build_a(aB0a, aB0b, wh1r0, w2a, w2b, lp0);
      short8 ag1 = build_a(aB1a, aB1b, wh1r1, w2a, w2b, lp1);
      if (k + 1 < NSTEP) {  // reload h1 adj for step k+1
        int jn = (k + 1) * KVBLK + 32;
        aB0a = *(const int4*)(aptr0 + jn);
        aB0b = *(const int4*)(aptr0 + jn + 4);
        aB1a = *(const int4*)(aptr1 + jn);
        aB1b = *(const int4*)(aptr1 + jn + 4);
      }
      const unsigned short* br = tb0 + bsel + off1;
#pragma unroll
      for (int h = 0; h < 4; ++h) {
        short8 bf[4];
#pragma unroll
        for (int t = 0; t < 4; ++t) bf[t] = *(const short8*)(br + (h * 4 + t) * 1024);
#pragma unroll
        for (int t = 0; t < 4; ++t) {
          acc0[h * 4 + t] =
              __builtin_amdgcn_mfma_f32_16x16x32_bf16(ag0, bf[t], acc0[h * 4 + t], 0, 0, 0);
          acc1[h * 4 + t] =
              __builtin_amdgcn_mfma_f32_16x16x32_bf16(ag1, bf[t], acc1[h * 4 + t], 0, 0, 0);
        }
      }
    }
  }

  // l reduction across q groups; rows unique per wave -> exactly one writer per
  // (strip, row): plain nontemporal store to the strip-private partial.
  lp0 += __shfl_xor(lp0, 16);
  lp0 += __shfl_xor(lp0, 32);
  lp1 += __shfl_xor(lp1, 16);
  lp1 += __shfl_xor(lp1, 32);
  if (lane < 16) {
    __builtin_nontemporal_store(lp0, &lgp[(size_t)s * NN + i0 + w * 32 + lane]);
    __builtin_nontemporal_store(lp1, &lgp[(size_t)s * NN + i0 + w * 32 + 16 + lane]);
  }
  // partial O -> strip-private slab, plain nontemporal stores (NO atomics).
  float* slab = accs + (size_t)s * NN * DOUT;
#pragma unroll
  for (int T = 0; T < 16; ++T) {
    floatx4 v0 = acc0[T];
    floatx4 v1 = acc1[T];
    int dcol = T * 16 + col;
    int irow0 = i0 + w * 32 + q * 4;
#pragma unroll
    for (int r = 0; r < 4; ++r)
      __builtin_nontemporal_store(v0[r], &slab[(size_t)(irow0 + r) * DOUT + dcol]);
#pragma unroll
    for (int r = 0; r < 4; ++r)
      __builtin_nontemporal_store(v1[r], &slab[(size_t)(irow0 + 16 + r) * DOUT + dcol]);
  }
}

// ------- merge 8 strip slabs + lg partials, normalize + ELU -> fp32 out -------
__global__ __launch_bounds__(256) void kt_merge(const float* __restrict__ accs,
                                                const float* __restrict__ lgp,
                                                float* __restrict__ out) {
  int g = blockIdx.x * 256 + threadIdx.x;  // one 4-float group; 2048*256*4 = NN*DOUT
  int i = g >> 6;
  float l = 0.f;
#pragma unroll
  for (int s = 0; s < NSPLIT; ++s) l += lgp[(size_t)s * NN + i];
  float4 a = *(const float4*)(accs + (size_t)g * 4);
#pragma unroll
  for (int s = 1; s < NSPLIT; ++s) {
    float4 b = *(const float4*)(accs + (size_t)s * NN * DOUT + (size_t)g * 4);
    a.x += b.x; a.y += b.y; a.z += b.z; a.w += b.w;
  }
  float inv = 1.0f / l;
  float o[4] = {a.x * inv, a.y * inv, a.z * inv, a.w * inv};
#pragma unroll
  for (int r = 0; r < 4; ++r) o[r] = o[r] > 0.f ? o[r] : (__expf(o[r]) - 1.f);
  *(float4*)(out + (size_t)g * 4) = make_float4(o[0], o[1], o[2], o[3]);
}

extern "C" void kernel_launch(void* const* d_in, const int* in_sizes, int n_in,
                              void* d_out, int out_size, void* d_ws, size_t ws_size,
                              hipStream_t stream) {
  const float* X = (const float*)d_in[0];   // input fp32 [8192][512]
  const int* adj = (const int*)d_in[1];     // int32 [8192][8192]
  const float* Wg = (const float*)d_in[2];  // weight fp32 [512][256]
  const float* Ab = (const float*)d_in[3];  // a fp32 [512]
  float* out = (float*)d_out;               // fp32 [8192][256]

  // workspace: accs[8 slabs, 64 MB] | lgp[8][NN] | Wh1 | Wh2 | WT | WhTb (~81 MB
  // of the 1-GiB ws). Xb (bf16 X, 8 MB) aliases slab 0 (gemm1 consumes it
  // before attn writes slabs). WhTb = 32-j-blocked layout [j>>5][d][j&31].
  // NOTE: harness re-poisons the full ws (+restores inputs) between iterations
  // (~240us fixed tax in dur_us, visible as 1-GiB fillBuffer in rocprof) —
  // nothing may rely on ws persistence; only kernel time is addressable.
  char* ws = (char*)d_ws;
  float* accs = (float*)ws;                  // 8 x 8 MB slabs
  unsigned short* Xb = (unsigned short*)ws;  // alias of slab 0
  size_t off = (size_t)NSPLIT * NN * DOUT * 4;  // 64 MB
  float* lgp = (float*)(ws + off);
  off += (size_t)NSPLIT * NN * 4;  // 256 KB
  float* Wh1 = (float*)(ws + off);
  off += (size_t)NN * 4;
  float* Wh2 = (float*)(ws + off);
  off += (size_t)NN * 4;
  unsigned short* WT = (unsigned short*)(ws + off);
  off += (size_t)DOUT * DIN * 2;  // 256 KB
  unsigned short* WhTb = (unsigned short*)(ws + off);
  off += (size_t)DOUT * NN * 2;  // 4 MB

  hipMemsetAsync(Wh1, 0, (size_t)NN * 8, stream);  // Wh1+Wh2 (contiguous)
  kt_cvtx<<<2048, 256, 0, stream>>>(X, Xb);
  kt_transpose<<<128, 256, 0, stream>>>(Wg, WT);
  kt_gemm1<<<512, 256, 0, stream>>>(Xb, WT, Ab, WhTb, Wh1, Wh2);
  kt_attn<<<(NN / 128) * NSPLIT, 256, 0, stream>>>(adj, WhTb, Wh1, Wh2, accs, lgp);
  kt_merge<<<2048, 256, 0, stream>>>(accs, lgp, out);
}

// Round 11
// 443.360 us; speedup vs baseline: 1.0040x; 1.0040x over previous
//
#include <hip/hip_runtime.h>
#include <hip/hip_bf16.h>
#include <stdint.h>

#define NN 8192
#define DIN 512
#define DOUT 256
#define NSPLIT 8
#define STRIP (NN / NSPLIT) /* 1024 */
#define KVBLK 64
#define NSTEP (STRIP / KVBLK) /* 16 */
#define LOG2E 1.4426950408889634f

#ifdef __has_builtin
#if __has_builtin(__builtin_amdgcn_global_load_lds)
#define HAVE_GLL 1
#endif
#endif
#ifndef HAVE_GLL
#define HAVE_GLL 0
#endif

typedef short short8 __attribute__((ext_vector_type(8)));
typedef float floatx4 __attribute__((ext_vector_type(4)));

__device__ __forceinline__ unsigned short f2bf_rne(float x) {
  unsigned u = __float_as_uint(x);
  u += 0x7fffu + ((u >> 16) & 1u);
  return (unsigned short)(u >> 16);
}

// packed RNE f32->bf16 pair: low16 = bf16(lo), high16 = bf16(hi)
__device__ __forceinline__ unsigned cvt_pk_bf16(float lo, float hi) {
  unsigned r;
  asm("v_cvt_pk_bf16_f32 %0, %1, %2" : "=v"(r) : "v"(lo), "v"(hi));
  return r;
}

// 16-B global->LDS direct DMA (m97 structure). lds: wave-uniform base; HW writes
// base + lane*16. g: per-lane source. Fallback: plain load+ds_write.
__device__ __forceinline__ void stage16(unsigned short* lds, const unsigned short* g,
                                        int lane) {
#if HAVE_GLL
  __builtin_amdgcn_global_load_lds(
      (const __attribute__((address_space(1))) unsigned int*)(g + lane * 8),
      (__attribute__((address_space(3))) unsigned int*)lds, 16, 0, 0);
#else
  *(short8*)(lds + lane * 8) = *(const short8*)(g + lane * 8);
#endif
}

// -------- weight transpose+cvt: W fp32 [512][256] -> WT bf16 [256][512] --------
__global__ __launch_bounds__(256) void kt_transpose(const float* __restrict__ Wg,
                                                    unsigned short* __restrict__ WT) {
  __shared__ unsigned short sm[32][33];
  int tid = threadIdx.x;
  int bk = blockIdx.x >> 3;  // k tile
  int bn = blockIdx.x & 7;   // n tile
  int k0 = bk * 32, n0 = bn * 32;
  int r = tid >> 3, c4 = (tid & 7) * 4;
  const float* src = Wg + (size_t)(k0 + r) * DOUT + n0 + c4;
#pragma unroll
  for (int x = 0; x < 4; ++x) sm[r][c4 + x] = f2bf_rne(src[x]);
  __syncthreads();
  unsigned short* dst = WT + (size_t)(n0 + r) * DIN + k0 + c4;
#pragma unroll
  for (int x = 0; x < 4; ++x) dst[x] = sm[c4 + x][r];
}

// -- GEMM1 (R5-proven LDS-staged structure). Changes vs R10:
//    (a) cvtx FUSED: stages X directly from fp32, converting in-register
//        (kills the kt_cvtx launch + 24 MB of traffic).
//    (b) WhTb written PRE-SWIZZLED: within each 16-KB block [256 d][32 j],
//        physical chunk = ((j&31)>>3) ^ ((d>>1)&3). attn's global_load_lds DMA
//        copies blocks linearly, so the LDS tile lands already bank-swizzled
//        (m173 pattern: swizzle the global source, keep LDS linear). --
__global__ __launch_bounds__(256, 2) void kt_gemm1(const float* __restrict__ X,
                                                   const unsigned short* __restrict__ WT,
                                                   const float* __restrict__ Ab,
                                                   unsigned short* __restrict__ WhTb,
                                                   float* __restrict__ Wh1,
                                                   float* __restrict__ Wh2) {
  __shared__ __align__(16) unsigned short xs[64 * DIN];  // 64 KB
  int tid = threadIdx.x;
  int w = tid >> 6, lane = tid & 63;
  int col = lane & 15, q = lane >> 4;
  int ib = blockIdx.x & 127;  // i block (64 each)
  int db = blockIdx.x >> 7;   // d block (64 each)
  int i0 = ib * 64;

  // ---- stage X tile from fp32: thread owns row sr, chunks l = (tid&3) + 4n ----
  int sr = tid >> 2, sc = tid & 3, sxor = sr & 7;
  const float* gX = X + (size_t)(i0 + sr) * DIN + sc * 8;
  unsigned short* lX = xs + sr * DIN;
#pragma unroll
  for (int n = 0; n < 16; n += 4) {
    float4 fa[4], fb[4];
#pragma unroll
    for (int j2 = 0; j2 < 4; ++j2) {
      fa[j2] = *(const float4*)(gX + (n + j2) * 32);
      fb[j2] = *(const float4*)(gX + (n + j2) * 32 + 4);
    }
#pragma unroll
    for (int j2 = 0; j2 < 4; ++j2) {
      union { unsigned u[4]; short8 s8; } rr;
      rr.u[0] = cvt_pk_bf16(fa[j2].x, fa[j2].y);
      rr.u[1] = cvt_pk_bf16(fa[j2].z, fa[j2].w);
      rr.u[2] = cvt_pk_bf16(fb[j2].x, fb[j2].y);
      rr.u[3] = cvt_pk_bf16(fb[j2].z, fb[j2].w);
      int l = sc + (n + j2) * 4;
      *(short8*)(lX + ((l ^ sxor) * 8)) = rr.s8;
    }
  }

  // ---- prefetch all 16 A-frags (fly during the barrier drain) ----
  int drow = db * 64 + w * 16 + col;  // A row (d)
  const unsigned short* abase = WT + (size_t)drow * DIN + q * 8;
  short8 af[16];
#pragma unroll
  for (int s = 0; s < 16; ++s) af[s] = *(const short8*)(abase + s * 32);

  __syncthreads();

  floatx4 acc[4];
#pragma unroll
  for (int t = 0; t < 4; ++t) acc[t] = (floatx4)(0.0f);
  int cx = col & 7;  // reader XOR: (t*16+col)&7 == col&7
#pragma unroll
  for (int s = 0; s < 16; ++s) {
#pragma unroll
    for (int t = 0; t < 4; ++t) {
      short8 bf = *(const short8*)(xs + (t * 16 + col) * DIN + (((s * 4 + q) ^ cx) * 8));
      acc[t] = __builtin_amdgcn_mfma_f32_16x16x32_bf16(af[s], bf, acc[t], 0, 0, 0);
    }
  }

  // D: col=lane&15 -> i; row=q*4+r -> d  (layout verified vs anchor)
  int dq = db * 64 + w * 16 + q * 4;
  float a1v[4], a2v[4];
#pragma unroll
  for (int r = 0; r < 4; ++r) {
    a1v[r] = Ab[dq + r] * LOG2E;
    a2v[r] = Ab[DOUT + dq + r] * LOG2E;
  }
#pragma unroll
  for (int t = 0; t < 4; ++t) {
    floatx4 v = acc[t];
    int icol = i0 + t * 16 + col;  // attention j index
    int g = icol >> 5, c = (icol >> 3) & 3, e = icol & 7;
#pragma unroll
    for (int r = 0; r < 4; ++r) {
      int d = dq + r;
      WhTb[(size_t)g * 8192 + (size_t)d * 32 + ((c ^ ((d >> 1) & 3)) * 8) + e] =
          f2bf_rne(v[r]);
    }
    float p1 = v[0] * a1v[0] + v[1] * a1v[1] + v[2] * a1v[2] + v[3] * a1v[3];
    float p2 = v[0] * a2v[0] + v[1] * a2v[1] + v[2] * a2v[2] + v[3] * a2v[3];
    p1 += __shfl_xor(p1, 16);
    p1 += __shfl_xor(p1, 32);
    p2 += __shfl_xor(p2, 16);
    p2 += __shfl_xor(p2, 32);
    if (q == 0) {
      atomicAdd(&Wh1[icol], p1);
      atomicAdd(&Wh2[icol], p2);
    }
  }
}

// ---------------- fused masked-softmax attention (rank-1 scores) ----------------
// Max-free softmax is exact: |score*log2e| <= ~15, exp2 can't overflow; masked w=0.
// P weights rounded to bf16 (RNE) for MFMA; denominator sums the rounded weights.
// Wh1/Wh2 arrive pre-scaled by log2(e).
__device__ __forceinline__ short8 build_a(int4 pa, int4 pb, float wh1, floatx4 w2a,
                                          floatx4 w2b, float& lsum) {
  int av[8] = {pa.x, pa.y, pa.z, pa.w, pb.x, pb.y, pb.z, pb.w};
  float w2[8] = {w2a[0], w2a[1], w2a[2], w2a[3], w2b[0], w2b[1], w2b[2], w2b[3]};
  float wv[8];
#pragma unroll
  for (int e = 0; e < 8; ++e) {
    float sc = wh1 + w2[e];
    sc = fmaxf(sc, 0.2f * sc);  // LeakyReLU (commutes with the positive log2e scale)
    float ex = __builtin_amdgcn_exp2f(sc);
    wv[e] = (av[e] != 0) ? ex : 0.0f;
  }
  union { unsigned u[4]; short8 s8; } r;
#pragma unroll
  for (int p = 0; p < 4; ++p) {
    unsigned pk = cvt_pk_bf16(wv[2 * p], wv[2 * p + 1]);
    r.u[p] = pk;
    lsum += __uint_as_float(pk << 16) + __uint_as_float(pk & 0xffff0000u);
  }
  return r.s8;
}

// R11 attn: m97-structure staging. The per-step global->reg->ds_write chain is
// replaced by global_load_lds DMA (zero regs, zero ds_writes, no vmcnt-before-
// ds_write): tile_{k+1} DMA is issued RIGHT AFTER __syncthreads(k) into the
// other buffer (safe: barrier retired all waves' buffer reads), giving it a
// full step of flight before __syncthreads(k+1) drains it. adj is prefetched
// mid-step -> also pre-drained at the barrier, so build_a starts stall-free.
// LDS tile [2 buf][2 half][256 d][32 j], banks: gemm1 pre-swizzled the blocks
// (chunk ^= (d>>1)&3) -> reader phys = q ^ ((col>>1)&3) puts a uniform 8 lanes
// per 16-B slot = conflict-free. Epilogue (slab stores, no atomics) = R8.
__global__ __launch_bounds__(256, 2) void kt_attn(const int* __restrict__ adj,
                                                  const unsigned short* __restrict__ WhTb,
                                                  const float* __restrict__ Wh1,
                                                  const float* __restrict__ Wh2,
                                                  float* __restrict__ accs,
                                                  float* __restrict__ lgp) {
  __shared__ __align__(16) unsigned short tileB[2 * 2 * 8192];  // 64 KB
  __shared__ __align__(16) float wh2s[STRIP];                   // 4 KB
  int tid = threadIdx.x;
  int w = tid >> 6, lane = tid & 63;
  int col = lane & 15, q = lane >> 4;
  int s = blockIdx.x & (NSPLIT - 1);  // strip -> XCD: WhTb strip stays in that L2
  int ib = blockIdx.x >> 3;
  int i0 = ib * 128;
  int jb = s * STRIP;

  // Wh2 strip -> LDS once (256 threads x float4 = 1024 floats)
  ((float4*)wh2s)[tid] = ((const float4*)(Wh2 + jb))[tid];

  int r0 = i0 + w * 32 + col;  // this lane's first score row
  float wh1r0 = Wh1[r0];
  float wh1r1 = Wh1[r0 + 16];

  // staging source: strip = 32 pre-swizzled 16-KB blocks; step k = blocks 2k,2k+1
  const unsigned short* gW = WhTb + (size_t)(s * 32) * 8192;
  int wq = w * 4;  // this wave's 4 chunk-slots per half

  // reader: half n at base n*8192; row d = t*16+col, phys chunk q ^ ((col>>1)&3)
  int kq = (col >> 1) & 3;
  int off0 = col * 32 + ((q ^ kq) * 8);
  const unsigned short* tb0 = &tileB[0];

  const int* aptr0 = adj + ((size_t)r0 << 13) + jb + q * 8;
  const int* aptr1 = adj + ((size_t)(r0 + 16) << 13) + jb + q * 8;

  floatx4 acc0[16], acc1[16];
#pragma unroll
  for (int t = 0; t < 16; ++t) {
    acc0[t] = (floatx4)(0.0f);
    acc1[t] = (floatx4)(0.0f);
  }
  float lp0 = 0.f, lp1 = 0.f;

  // prologue: DMA tile 0 into buf0 + adj step-0 loads (drained by 1st barrier)
#pragma unroll
  for (int n = 0; n < 2; ++n)
#pragma unroll
    for (int m = 0; m < 4; ++m)
      stage16(&tileB[n * 8192 + (wq + m) * 512], gW + n * 8192 + (wq + m) * 512, lane);
  int4 aA0a = *(const int4*)aptr0;         // h0 row0
  int4 aA0b = *(const int4*)(aptr0 + 4);
  int4 aA1a = *(const int4*)aptr1;         // h0 row1
  int4 aA1b = *(const int4*)(aptr1 + 4);
  int4 aB0a = *(const int4*)(aptr0 + 32);  // h1 row0
  int4 aB0b = *(const int4*)(aptr0 + 36);
  int4 aB1a = *(const int4*)(aptr1 + 32);  // h1 row1
  int4 aB1b = *(const int4*)(aptr1 + 36);

#pragma unroll 1
  for (int k = 0; k < NSTEP; ++k) {
    // drains: tile_k DMA (vm, issued a full step ago), adj_k (vm, ~2/3 step ago),
    // own ds_reads of the other buffer (lgkm) -> all flight-covered, ~no stall.
    __syncthreads();
    int bsel = (k & 1) * 16384;
    if (k + 1 < NSTEP) {  // DMA next tile into the buffer everyone just finished
      const unsigned short* gs = gW + (size_t)(2 * (k + 1)) * 8192;
      unsigned short* ls = &tileB[((k + 1) & 1) * 16384];
#pragma unroll
      for (int n = 0; n < 2; ++n)
#pragma unroll
        for (int m = 0; m < 4; ++m)
          stage16(ls + n * 8192 + (wq + m) * 512, gs + n * 8192 + (wq + m) * 512, lane);
    }
    int jl = k * KVBLK;
    // ---------------- half 0 (j = jl .. jl+32) ----------------
    {
      floatx4 w2a = *(const floatx4*)&wh2s[jl + q * 8];
      floatx4 w2b = *(const floatx4*)&wh2s[jl + q * 8 + 4];
      short8 af0 = build_a(aA0a, aA0b, wh1r0, w2a, w2b, lp0);
      short8 af1 = build_a(aA1a, aA1b, wh1r1, w2a, w2b, lp1);
      if (k + 1 < NSTEP) {  // prefetch h0 adj for step k+1
        int jn = (k + 1) * KVBLK;
        aA0a = *(const int4*)(aptr0 + jn);
        aA0b = *(const int4*)(aptr0 + jn + 4);
        aA1a = *(const int4*)(aptr1 + jn);
        aA1b = *(const int4*)(aptr1 + jn + 4);
      }
      const unsigned short* br = tb0 + bsel + off0;
#pragma unroll
      for (int h = 0; h < 4; ++h) {
        short8 bf[4];
#pragma unroll
        for (int t = 0; t < 4; ++t) bf[t] = *(const short8*)(br + (h * 4 + t) * 512);
#pragma unroll
        for (int t = 0; t < 4; ++t) {
          acc0[h * 4 + t] =
              __builtin_amdgcn_mfma_f32_16x16x32_bf16(af0, bf[t], acc0[h * 4 + t], 0, 0, 0);
          acc1[h * 4 + t] =
              __builtin_amdgcn_mfma_f32_16x16x32_bf16(af1, bf[t], acc1[h * 4 + t], 0, 0, 0);
        }
      }
    }
    // ---------------- half 1 (j = jl+32 .. jl+64) ----------------
    {
      floatx4 w2a = *(const floatx4*)&wh2s[jl + 32 + q * 8];
      floatx4 w2b = *(const floatx4*)&wh2s[jl + 32 + q * 8 + 4];
      short8 ag0 = build_a(aB0a, aB0b, wh1r0, w2a, w2b, lp0);
      short8 ag1 = build_a(aB1a, aB1b, wh1r1, w2a, w2b, lp1);
      if (k + 1 < NSTEP) {  // prefetch h1 adj for step k+1
        int jn = (k + 1) * KVBLK + 32;
        aB0a = *(const int4*)(aptr0 + jn);
        aB0b = *(const int4*)(aptr0 + jn + 4);
        aB1a = *(const int4*)(aptr1 + jn);
        aB1b = *(const int4*)(aptr1 + jn + 4);
      }
      const unsigned short* br = tb0 + bsel + 8192 + off0;
#pragma unroll
      for (int h = 0; h < 4; ++h) {
        short8 bf[4];
#pragma unroll
        for (int t = 0; t < 4; ++t) bf[t] = *(const short8*)(br + (h * 4 + t) * 512);
#pragma unroll
        for (int t = 0; t < 4; ++t) {
          acc0[h * 4 + t] =
              __builtin_amdgcn_mfma_f32_16x16x32_bf16(ag0, bf[t], acc0[h * 4 + t], 0, 0, 0);
          acc1[h * 4 + t] =
              __builtin_amdgcn_mfma_f32_16x16x32_bf16(ag1, bf[t], acc1[h * 4 + t], 0, 0, 0);
        }
      }
    }
  }

  // l reduction across q groups; rows unique per wave -> exactly one writer per
  // (strip, row): plain nontemporal store to the strip-private partial.
  lp0 += __shfl_xor(lp0, 16);
  lp0 += __shfl_xor(lp0, 32);
  lp1 += __shfl_xor(lp1, 16);
  lp1 += __shfl_xor(lp1, 32);
  if (lane < 16) {
    __builtin_nontemporal_store(lp0, &lgp[(size_t)s * NN + i0 + w * 32 + lane]);
    __builtin_nontemporal_store(lp1, &lgp[(size_t)s * NN + i0 + w * 32 + 16 + lane]);
  }
  // partial O -> strip-private slab, plain nontemporal stores (NO atomics).
  float* slab = accs + (size_t)s * NN * DOUT;
#pragma unroll
  for (int T = 0; T < 16; ++T) {
    floatx4 v0 = acc0[T];
    floatx4 v1 = acc1[T];
    int dcol = T * 16 + col;
    int irow0 = i0 + w * 32 + q * 4;
#pragma unroll
    for (int r = 0; r < 4; ++r)
      __builtin_nontemporal_store(v0[r], &slab[(size_t)(irow0 + r) * DOUT + dcol]);
#pragma unroll
    for (int r = 0; r < 4; ++r)
      __builtin_nontemporal_store(v1[r], &slab[(size_t)(irow0 + 16 + r) * DOUT + dcol]);
  }
}

// ------- merge 8 strip slabs + lg partials, normalize + ELU -> fp32 out -------
__global__ __launch_bounds__(256) void kt_merge(const float* __restrict__ accs,
                                                const float* __restrict__ lgp,
                                                float* __restrict__ out) {
  int g = blockIdx.x * 256 + threadIdx.x;  // one 4-float group; 2048*256*4 = NN*DOUT
  int i = g >> 6;
  float l = 0.f;
#pragma unroll
  for (int s = 0; s < NSPLIT; ++s) l += lgp[(size_t)s * NN + i];
  float4 a = *(const float4*)(accs + (size_t)g * 4);
#pragma unroll
  for (int s = 1; s < NSPLIT; ++s) {
    float4 b = *(const float4*)(accs + (size_t)s * NN * DOUT + (size_t)g * 4);
    a.x += b.x; a.y += b.y; a.z += b.z; a.w += b.w;
  }
  float inv = 1.0f / l;
  float o[4] = {a.x * inv, a.y * inv, a.z * inv, a.w * inv};
#pragma unroll
  for (int r = 0; r < 4; ++r) o[r] = o[r] > 0.f ? o[r] : (__expf(o[r]) - 1.f);
  *(float4*)(out + (size_t)g * 4) = make_float4(o[0], o[1], o[2], o[3]);
}

extern "C" void kernel_launch(void* const* d_in, const int* in_sizes, int n_in,
                              void* d_out, int out_size, void* d_ws, size_t ws_size,
                              hipStream_t stream) {
  const float* X = (const float*)d_in[0];   // input fp32 [8192][512]
  const int* adj = (const int*)d_in[1];     // int32 [8192][8192]
  const float* Wg = (const float*)d_in[2];  // weight fp32 [512][256]
  const float* Ab = (const float*)d_in[3];  // a fp32 [512]
  float* out = (float*)d_out;               // fp32 [8192][256]

  // workspace: accs[8 slabs, 64 MB] | lgp[8][NN] | Wh1 | Wh2 | WT | WhTb.
  // WhTb = pre-swizzled 16-KB-blocked layout (see gemm1). cvtx is gone (fused
  // into gemm1), so no Xb alias. NOTE: harness re-poisons the full ws between
  // iterations (~240us fixed tax, 1-GiB fillBuffer in rocprof) — nothing may
  // rely on ws persistence; only kernel time is addressable.
  char* ws = (char*)d_ws;
  float* accs = (float*)ws;                     // 8 x 8 MB slabs
  size_t off = (size_t)NSPLIT * NN * DOUT * 4;  // 64 MB
  float* lgp = (float*)(ws + off);
  off += (size_t)NSPLIT * NN * 4;  // 256 KB
  float* Wh1 = (float*)(ws + off);
  off += (size_t)NN * 4;
  float* Wh2 = (float*)(ws + off);
  off += (size_t)NN * 4;
  unsigned short* WT = (unsigned short*)(ws + off);
  off += (size_t)DOUT * DIN * 2;  // 256 KB
  unsigned short* WhTb = (unsigned short*)(ws + off);
  off += (size_t)DOUT * NN * 2;  // 4 MB

  hipMemsetAsync(Wh1, 0, (size_t)NN * 8, stream);  // Wh1+Wh2 (contiguous)
  kt_transpose<<<128, 256, 0, stream>>>(Wg, WT);
  kt_gemm1<<<512, 256, 0, stream>>>(X, WT, Ab, WhTb, Wh1, Wh2);
  kt_attn<<<(NN / 128) * NSPLIT, 256, 0, stream>>>(adj, WhTb, Wh1, Wh2, accs, lgp);
  kt_merge<<<2048, 256, 0, stream>>>(accs, lgp, out);
}

// Round 12
// 434.978 us; speedup vs baseline: 1.0234x; 1.0193x over previous
//
#include <hip/hip_runtime.h>
#include <hip/hip_bf16.h>
#include <stdint.h>

#define NN 8192
#define DIN 512
#define DOUT 256
#define NSPLIT 8
#define STRIP (NN / NSPLIT) /* 1024 */
#define KVBLK 64
#define NSTEP (STRIP / KVBLK) /* 16 */
#define LOG2E 1.4426950408889634f

#ifdef __has_builtin
#if __has_builtin(__builtin_amdgcn_global_load_lds)
#define HAVE_GLL 1
#endif
#endif
#ifndef HAVE_GLL
#define HAVE_GLL 0
#endif

typedef short short8 __attribute__((ext_vector_type(8)));
typedef float floatx4 __attribute__((ext_vector_type(4)));

__device__ __forceinline__ unsigned short f2bf_rne(float x) {
  unsigned u = __float_as_uint(x);
  u += 0x7fffu + ((u >> 16) & 1u);
  return (unsigned short)(u >> 16);
}

// packed RNE f32->bf16 pair: low16 = bf16(lo), high16 = bf16(hi)
__device__ __forceinline__ unsigned cvt_pk_bf16(float lo, float hi) {
  unsigned r;
  asm("v_cvt_pk_bf16_f32 %0, %1, %2" : "=v"(r) : "v"(lo), "v"(hi));
  return r;
}

// 16-B global->LDS direct DMA (m97 structure). lds: wave-uniform base; HW writes
// base + lane*16. g: per-lane source. Fallback: plain load+ds_write.
__device__ __forceinline__ void stage16(unsigned short* lds, const unsigned short* g,
                                        int lane) {
#if HAVE_GLL
  __builtin_amdgcn_global_load_lds(
      (const __attribute__((address_space(1))) unsigned int*)(g + lane * 8),
      (__attribute__((address_space(3))) unsigned int*)lds, 16, 0, 0);
#else
  *(short8*)(lds + lane * 8) = *(const short8*)(g + lane * 8);
#endif
}

// -------- weight transpose+cvt: W fp32 [512][256] -> WT bf16 [256][512] --------
__global__ __launch_bounds__(256) void kt_transpose(const float* __restrict__ Wg,
                                                    unsigned short* __restrict__ WT) {
  __shared__ unsigned short sm[32][33];
  int tid = threadIdx.x;
  int bk = blockIdx.x >> 3;  // k tile
  int bn = blockIdx.x & 7;   // n tile
  int k0 = bk * 32, n0 = bn * 32;
  int r = tid >> 3, c4 = (tid & 7) * 4;
  const float* src = Wg + (size_t)(k0 + r) * DOUT + n0 + c4;
#pragma unroll
  for (int x = 0; x < 4; ++x) sm[r][c4 + x] = f2bf_rne(src[x]);
  __syncthreads();
  unsigned short* dst = WT + (size_t)(n0 + r) * DIN + k0 + c4;
#pragma unroll
  for (int x = 0; x < 4; ++x) dst[x] = sm[c4 + x][r];
}

// -- GEMM1 (R11-proven): fused fp32->bf16 X staging; WhTb written PRE-SWIZZLED
//    16-KB-blocked: block g = j>>5, element (d, j&31), physical chunk
//    = ((j&31)>>3) ^ ((d>>1)&3). attn's DMA copies blocks linearly, so the LDS
//    tile lands already bank-swizzled (m173 pattern). --
__global__ __launch_bounds__(256, 2) void kt_gemm1(const float* __restrict__ X,
                                                   const unsigned short* __restrict__ WT,
                                                   const float* __restrict__ Ab,
                                                   unsigned short* __restrict__ WhTb,
                                                   float* __restrict__ Wh1,
                                                   float* __restrict__ Wh2) {
  __shared__ __align__(16) unsigned short xs[64 * DIN];  // 64 KB
  int tid = threadIdx.x;
  int w = tid >> 6, lane = tid & 63;
  int col = lane & 15, q = lane >> 4;
  int ib = blockIdx.x & 127;  // i block (64 each)
  int db = blockIdx.x >> 7;   // d block (64 each)
  int i0 = ib * 64;

  // ---- stage X tile from fp32: thread owns row sr, chunks l = (tid&3) + 4n ----
  int sr = tid >> 2, sc = tid & 3, sxor = sr & 7;
  const float* gX = X + (size_t)(i0 + sr) * DIN + sc * 8;
  unsigned short* lX = xs + sr * DIN;
#pragma unroll
  for (int n = 0; n < 16; n += 4) {
    float4 fa[4], fb[4];
#pragma unroll
    for (int j2 = 0; j2 < 4; ++j2) {
      fa[j2] = *(const float4*)(gX + (n + j2) * 32);
      fb[j2] = *(const float4*)(gX + (n + j2) * 32 + 4);
    }
#pragma unroll
    for (int j2 = 0; j2 < 4; ++j2) {
      union { unsigned u[4]; short8 s8; } rr;
      rr.u[0] = cvt_pk_bf16(fa[j2].x, fa[j2].y);
      rr.u[1] = cvt_pk_bf16(fa[j2].z, fa[j2].w);
      rr.u[2] = cvt_pk_bf16(fb[j2].x, fb[j2].y);
      rr.u[3] = cvt_pk_bf16(fb[j2].z, fb[j2].w);
      int l = sc + (n + j2) * 4;
      *(short8*)(lX + ((l ^ sxor) * 8)) = rr.s8;
    }
  }

  // ---- prefetch all 16 A-frags (fly during the barrier drain) ----
  int drow = db * 64 + w * 16 + col;  // A row (d)
  const unsigned short* abase = WT + (size_t)drow * DIN + q * 8;
  short8 af[16];
#pragma unroll
  for (int s = 0; s < 16; ++s) af[s] = *(const short8*)(abase + s * 32);

  __syncthreads();

  floatx4 acc[4];
#pragma unroll
  for (int t = 0; t < 4; ++t) acc[t] = (floatx4)(0.0f);
  int cx = col & 7;  // reader XOR: (t*16+col)&7 == col&7
#pragma unroll
  for (int s = 0; s < 16; ++s) {
#pragma unroll
    for (int t = 0; t < 4; ++t) {
      short8 bf = *(const short8*)(xs + (t * 16 + col) * DIN + (((s * 4 + q) ^ cx) * 8));
      acc[t] = __builtin_amdgcn_mfma_f32_16x16x32_bf16(af[s], bf, acc[t], 0, 0, 0);
    }
  }

  // D: col=lane&15 -> i; row=q*4+r -> d  (layout verified vs anchor)
  int dq = db * 64 + w * 16 + q * 4;
  float a1v[4], a2v[4];
#pragma unroll
  for (int r = 0; r < 4; ++r) {
    a1v[r] = Ab[dq + r] * LOG2E;
    a2v[r] = Ab[DOUT + dq + r] * LOG2E;
  }
#pragma unroll
  for (int t = 0; t < 4; ++t) {
    floatx4 v = acc[t];
    int icol = i0 + t * 16 + col;  // attention j index
    int g = icol >> 5, c = (icol >> 3) & 3, e = icol & 7;
#pragma unroll
    for (int r = 0; r < 4; ++r) {
      int d = dq + r;
      WhTb[(size_t)g * 8192 + (size_t)d * 32 + ((c ^ ((d >> 1) & 3)) * 8) + e] =
          f2bf_rne(v[r]);
    }
    float p1 = v[0] * a1v[0] + v[1] * a1v[1] + v[2] * a1v[2] + v[3] * a1v[3];
    float p2 = v[0] * a2v[0] + v[1] * a2v[1] + v[2] * a2v[2] + v[3] * a2v[3];
    p1 += __shfl_xor(p1, 16);
    p1 += __shfl_xor(p1, 32);
    p2 += __shfl_xor(p2, 16);
    p2 += __shfl_xor(p2, 32);
    if (q == 0) {
      atomicAdd(&Wh1[icol], p1);
      atomicAdd(&Wh2[icol], p2);
    }
  }
}

// ---------------- fused masked-softmax attention (rank-1 scores) ----------------
// Max-free softmax is exact: |score*log2e| <= ~15, exp2 can't overflow; masked w=0.
// P weights rounded to bf16 (RNE) for MFMA; denominator sums the rounded weights.
// Wh1/Wh2 arrive pre-scaled by log2(e).
__device__ __forceinline__ short8 build_a(int4 pa, int4 pb, float wh1, floatx4 w2a,
                                          floatx4 w2b, float& lsum) {
  int av[8] = {pa.x, pa.y, pa.z, pa.w, pb.x, pb.y, pb.z, pb.w};
  float w2[8] = {w2a[0], w2a[1], w2a[2], w2a[3], w2b[0], w2b[1], w2b[2], w2b[3]};
  float wv[8];
#pragma unroll
  for (int e = 0; e < 8; ++e) {
    float sc = wh1 + w2[e];
    sc = fmaxf(sc, 0.2f * sc);  // LeakyReLU (commutes with the positive log2e scale)
    float ex = __builtin_amdgcn_exp2f(sc);
    wv[e] = (av[e] != 0) ? ex : 0.0f;
  }
  union { unsigned u[4]; short8 s8; } r;
#pragma unroll
  for (int p = 0; p < 4; ++p) {
    unsigned pk = cvt_pk_bf16(wv[2 * p], wv[2 * p + 1]);
    r.u[p] = pk;
    lsum += __uint_as_float(pk << 16) + __uint_as_float(pk & 0xffff0000u);
  }
  return r.s8;
}

// R12 attn: OCCUPANCY TEST (single variable vs R11). 512-thread blocks, 8 waves
// x 16 rows each (block still 128 rows x 256 d, KVBLK=64). acc halves to 16
// floatx4 = 64 VGPR/wave; launch_bounds(512,4) caps regs at 128 -> 2 blocks/CU
// = 16 waves/CU = 4 waves/SIMD (2x R11's TLP). Per-CU work per step identical.
// DMA staging (R11), pre-swizzled reader, slab epilogue: mechanics unchanged.
__global__ __launch_bounds__(512, 4) void kt_attn(const int* __restrict__ adj,
                                                  const unsigned short* __restrict__ WhTb,
                                                  const float* __restrict__ Wh1,
                                                  const float* __restrict__ Wh2,
                                                  float* __restrict__ accs,
                                                  float* __restrict__ lgp) {
  __shared__ __align__(16) unsigned short tileB[2 * 2 * 8192];  // 64 KB
  __shared__ __align__(16) float wh2s[STRIP];                   // 4 KB
  int tid = threadIdx.x;
  int w = tid >> 6, lane = tid & 63;  // 8 waves
  int col = lane & 15, q = lane >> 4;
  int s = blockIdx.x & (NSPLIT - 1);  // strip -> XCD: WhTb strip stays in that L2
  int ib = blockIdx.x >> 3;
  int i0 = ib * 128;
  int jb = s * STRIP;

  // Wh2 strip -> LDS once (first 256 threads x float4 = 1024 floats)
  if (tid < 256) ((float4*)wh2s)[tid] = ((const float4*)(Wh2 + jb))[tid];

  int r0 = i0 + w * 16 + col;  // this lane's score row (16 rows per wave)
  float wh1r0 = Wh1[r0];

  // staging source: strip = 32 pre-swizzled 16-KB blocks; step k = blocks 2k,2k+1.
  // 32 one-KB chunks per step; wave w DMAs chunks c = w*4+m (half c>>4, slot c&15).
  const unsigned short* gW = WhTb + (size_t)(s * 32) * 8192;

  // reader: half n at base n*8192; row d = T*16+col, phys chunk q ^ ((col>>1)&3)
  int kq = (col >> 1) & 3;
  int off0 = col * 32 + ((q ^ kq) * 8);
  const unsigned short* tb0 = &tileB[0];

  const int* aptr0 = adj + ((size_t)r0 << 13) + jb + q * 8;

  floatx4 acc0[16];
#pragma unroll
  for (int t = 0; t < 16; ++t) acc0[t] = (floatx4)(0.0f);
  float lp0 = 0.f;

  // prologue: DMA tile 0 into buf0 + adj step-0 loads (drained by 1st barrier)
#pragma unroll
  for (int m = 0; m < 4; ++m) {
    int c = w * 4 + m;
    stage16(&tileB[(c >> 4) * 8192 + (c & 15) * 512], gW + (size_t)c * 512, lane);
  }
  int4 aA0a = *(const int4*)aptr0;         // half0
  int4 aA0b = *(const int4*)(aptr0 + 4);
  int4 aB0a = *(const int4*)(aptr0 + 32);  // half1
  int4 aB0b = *(const int4*)(aptr0 + 36);

#pragma unroll 1
  for (int k = 0; k < NSTEP; ++k) {
    // drains: tile_k DMA (vm, issued a full step ago), adj_k (vm, ~a step ago),
    // own ds_reads of the other buffer (lgkm) -> flight-covered.
    __syncthreads();
    int bsel = (k & 1) * 16384;
    if (k + 1 < NSTEP) {  // DMA next tile into the buffer everyone just finished
      const unsigned short* gs = gW + (size_t)(2 * (k + 1)) * 8192;
      unsigned short* ls = &tileB[((k + 1) & 1) * 16384];
#pragma unroll
      for (int m = 0; m < 4; ++m) {
        int c = w * 4 + m;
        stage16(ls + (c >> 4) * 8192 + (c & 15) * 512, gs + (size_t)c * 512, lane);
      }
    }
    int jl = k * KVBLK;
    // ---------------- half 0 (j = jl .. jl+32) ----------------
    {
      floatx4 w2a = *(const floatx4*)&wh2s[jl + q * 8];
      floatx4 w2b = *(const floatx4*)&wh2s[jl + q * 8 + 4];
      short8 af0 = build_a(aA0a, aA0b, wh1r0, w2a, w2b, lp0);
      if (k + 1 < NSTEP) {  // prefetch half0 adj for step k+1
        int jn = (k + 1) * KVBLK;
        aA0a = *(const int4*)(aptr0 + jn);
        aA0b = *(const int4*)(aptr0 + jn + 4);
      }
      const unsigned short* br = tb0 + bsel + off0;
#pragma unroll
      for (int h = 0; h < 4; ++h) {
        short8 bf[4];
#pragma unroll
        for (int t = 0; t < 4; ++t) bf[t] = *(const short8*)(br + (h * 4 + t) * 512);
#pragma unroll
        for (int t = 0; t < 4; ++t)
          acc0[h * 4 + t] =
              __builtin_amdgcn_mfma_f32_16x16x32_bf16(af0, bf[t], acc0[h * 4 + t], 0, 0, 0);
      }
    }
    // ---------------- half 1 (j = jl+32 .. jl+64) ----------------
    {
      floatx4 w2a = *(const floatx4*)&wh2s[jl + 32 + q * 8];
      floatx4 w2b = *(const floatx4*)&wh2s[jl + 32 + q * 8 + 4];
      short8 ag0 = build_a(aB0a, aB0b, wh1r0, w2a, w2b, lp0);
      if (k + 1 < NSTEP) {  // prefetch half1 adj for step k+1
        int jn = (k + 1) * KVBLK + 32;
        aB0a = *(const int4*)(aptr0 + jn);
        aB0b = *(const int4*)(aptr0 + jn + 4);
      }
      const unsigned short* br = tb0 + bsel + 8192 + off0;
#pragma unroll
      for (int h = 0; h < 4; ++h) {
        short8 bf[4];
#pragma unroll
        for (int t = 0; t < 4; ++t) bf[t] = *(const short8*)(br + (h * 4 + t) * 512);
#pragma unroll
        for (int t = 0; t < 4; ++t)
          acc0[h * 4 + t] =
              __builtin_amdgcn_mfma_f32_16x16x32_bf16(ag0, bf[t], acc0[h * 4 + t], 0, 0, 0);
      }
    }
  }

  // l reduction across q groups; 16 unique rows per wave -> one writer each.
  lp0 += __shfl_xor(lp0, 16);
  lp0 += __shfl_xor(lp0, 32);
  if (lane < 16)
    __builtin_nontemporal_store(lp0, &lgp[(size_t)s * NN + i0 + w * 16 + lane]);
  // partial O -> strip-private slab, plain nontemporal stores (NO atomics).
  float* slab = accs + (size_t)s * NN * DOUT;
#pragma unroll
  for (int T = 0; T < 16; ++T) {
    floatx4 v0 = acc0[T];
    int dcol = T * 16 + col;
    int irow0 = i0 + w * 16 + q * 4;
#pragma unroll
    for (int r = 0; r < 4; ++r)
      __builtin_nontemporal_store(v0[r], &slab[(size_t)(irow0 + r) * DOUT + dcol]);
  }
}

// ------- merge 8 strip slabs + lg partials, normalize + ELU -> fp32 out -------
__global__ __launch_bounds__(256) void kt_merge(const float* __restrict__ accs,
                                                const float* __restrict__ lgp,
                                                float* __restrict__ out) {
  int g = blockIdx.x * 256 + threadIdx.x;  // one 4-float group; 2048*256*4 = NN*DOUT
  int i = g >> 6;
  float l = 0.f;
#pragma unroll
  for (int s = 0; s < NSPLIT; ++s) l += lgp[(size_t)s * NN + i];
  float4 a = *(const float4*)(accs + (size_t)g * 4);
#pragma unroll
  for (int s = 1; s < NSPLIT; ++s) {
    float4 b = *(const float4*)(accs + (size_t)s * NN * DOUT + (size_t)g * 4);
    a.x += b.x; a.y += b.y; a.z += b.z; a.w += b.w;
  }
  float inv = 1.0f / l;
  float o[4] = {a.x * inv, a.y * inv, a.z * inv, a.w * inv};
#pragma unroll
  for (int r = 0; r < 4; ++r) o[r] = o[r] > 0.f ? o[r] : (__expf(o[r]) - 1.f);
  *(float4*)(out + (size_t)g * 4) = make_float4(o[0], o[1], o[2], o[3]);
}

extern "C" void kernel_launch(void* const* d_in, const int* in_sizes, int n_in,
                              void* d_out, int out_size, void* d_ws, size_t ws_size,
                              hipStream_t stream) {
  const float* X = (const float*)d_in[0];   // input fp32 [8192][512]
  const int* adj = (const int*)d_in[1];     // int32 [8192][8192]
  const float* Wg = (const float*)d_in[2];  // weight fp32 [512][256]
  const float* Ab = (const float*)d_in[3];  // a fp32 [512]
  float* out = (float*)d_out;               // fp32 [8192][256]

  // workspace: accs[8 slabs, 64 MB] | lgp[8][NN] | Wh1 | Wh2 | WT | WhTb.
  // WhTb = pre-swizzled 16-KB-blocked layout (see gemm1). NOTE: harness
  // re-poisons the full ws between iterations (~240us fixed tax, 1-GiB
  // fillBuffer in rocprof) — nothing may rely on ws persistence.
  char* ws = (char*)d_ws;
  float* accs = (float*)ws;                     // 8 x 8 MB slabs
  size_t off = (size_t)NSPLIT * NN * DOUT * 4;  // 64 MB
  float* lgp = (float*)(ws + off);
  off += (size_t)NSPLIT * NN * 4;  // 256 KB
  float* Wh1 = (float*)(ws + off);
  off += (size_t)NN * 4;
  float* Wh2 = (float*)(ws + off);
  off += (size_t)NN * 4;
  unsigned short* WT = (unsigned short*)(ws + off);
  off += (size_t)DOUT * DIN * 2;  // 256 KB
  unsigned short* WhTb = (unsigned short*)(ws + off);
  off += (size_t)DOUT * NN * 2;  // 4 MB

  hipMemsetAsync(Wh1, 0, (size_t)NN * 8, stream);  // Wh1+Wh2 (contiguous)
  kt_transpose<<<128, 256, 0, stream>>>(Wg, WT);
  kt_gemm1<<<512, 256, 0, stream>>>(X, WT, Ab, WhTb, Wh1, Wh2);
  kt_attn<<<(NN / 128) * NSPLIT, 512, 0, stream>>>(adj, WhTb, Wh1, Wh2, accs, lgp);
  kt_merge<<<2048, 256, 0, stream>>>(accs, lgp, out);
}